// Round 5
// baseline (310.672 us; speedup 1.0000x reference)
//
#include <hip/hip_runtime.h>
#include <math.h>

// SOINN+ restructured, round 13:
//  k_xx    : unchanged.
//  k_dist  : unchanged from round 9.
//  k_build : unchanged from round 8.
//  k_seq   : producer floor lowered; consumer byte-identical to R12.
//            Calibration from R10-R12: T = max(C, P/2) with C ~= P/2 ~= 1300cy
//            (adding consumer work extended T 1:1; removing it didn't help ->
//            sitting on the producer floor). So: 4 producer waves (320-thread
//            block), producer t on wave 1+(t%4), wait done[t-5]. Consumer
//            patches last-8 winners (bitmap misses steps t-4..t-1), spec
//            depth 12 rank-indexed, 8 rotating spec slots (t&7; slot reused
//            at t+8 only after done[t+3] -> no overwrite race). Producer
//            floor -> (C1+P)/5 ~= 600cy < C; period becomes consumer-bound.

#define N_NODES 100000
#define DIM     256
#define NS      64
#define NCH     1563
#define KC      32
#define NBMW    3125
#define CAP     4096
#define KL      192
#define KLS     136

typedef unsigned long long u64;

__device__ __forceinline__ u64 pk(float d, int i) {
  return ((u64)__float_as_uint(d) << 32) | (unsigned)i;
}
// tracked-provenance key: bit31 flag, slot<<17 (slot<128), node in low 17 bits
__device__ __forceinline__ u64 tkey(float d, int slot, int node) {
  return ((u64)__float_as_uint(d) << 32) |
         (u64)(0x80000000u | ((unsigned)slot << 17) | (unsigned)node);
}
__device__ __forceinline__ u64 umin64(u64 a, u64 b) { return a < b ? a : b; }
__device__ __forceinline__ u64 umax64(u64 a, u64 b) { return a > b ? a : b; }
__device__ __forceinline__ void mrg2(u64& A0, u64& A1, u64 B0, u64 B1) {
  u64 m = umax64(A0, B0);
  A0 = umin64(A0, B0);
  A1 = umin64(umin64(A1, B1), m);
}
__device__ __forceinline__ float rdlane_f(float v, int l) {
  return __uint_as_float((unsigned)__builtin_amdgcn_readlane(
      (int)__float_as_uint(v), l));
}

template <int C>
__device__ __forceinline__ u64 dpp64(u64 x) {
  unsigned lo = (unsigned)__builtin_amdgcn_update_dpp(
      (int)0xFFFFFFFF, (int)(unsigned)(x & 0xFFFFFFFFull), C, 0xF, 0xF, false);
  unsigned hi = (unsigned)__builtin_amdgcn_update_dpp(
      (int)0xFFFFFFFF, (int)(unsigned)(x >> 32), C, 0xF, 0xF, false);
  return ((u64)hi << 32) | lo;
}
template <int C>
__device__ __forceinline__ void dpp_round(u64& A0, u64& A1) {
  u64 B0 = dpp64<C>(A0);
  u64 B1 = dpp64<C>(A1);
  mrg2(A0, A1, B0, B1);
}

#define SPIN(flag)                                                        \
  while (__hip_atomic_load(&(flag), __ATOMIC_ACQUIRE,                     \
                           __HIP_MEMORY_SCOPE_WORKGROUP) == 0)            \
    __builtin_amdgcn_s_sleep(1);

__global__ void k_xx(const float* __restrict__ X, float* __restrict__ XX) {
  int i = blockIdx.x, j = threadIdx.x;
  const float* xi = X + i * DIM;
  const float* xj = X + j * DIM;
  float acc = 0.f;
  for (int k = 0; k < DIM; k += 4) {
    float4 a = *(const float4*)(xi + k);
    float4 b = *(const float4*)(xj + k);
    acc += a.x * b.x + a.y * b.y + a.z * b.z + a.w * b.w;
  }
  XX[i * NS + j] = acc;
}

__global__ __launch_bounds__(256) void k_dist(const float* __restrict__ X,
                                              const float* __restrict__ V,
                                              const float* __restrict__ XX,
                                              float* __restrict__ P,
                                              float* __restrict__ PT,
                                              float* __restrict__ Q,
                                              u64* __restrict__ SUMC) {
  __shared__ float Xl[KC][68];     // 64 samples, k-major
  __shared__ float Vl[KC][132];    // 128 nodes, k-major (+4 pad; rows 16B-aligned)
  __shared__ float sq[128];
  const int tid = threadIdx.x;     // 256 threads
  const int n0  = blockIdx.x * 128;
  const int ty  = tid >> 5;        // 0..7  -> samples 8ty..8ty+7
  const int tx  = tid & 31;        // 0..31 -> nodes 4tx..4tx+3 (stride-4: bank-optimal)
  float acc[8][4];
#pragma unroll
  for (int i = 0; i < 8; i++)
#pragma unroll
    for (int u = 0; u < 4; u++) acc[i][u] = 0.f;
  float qa = 0.f;
  const int xsl = tid & 63;            // sample row for X staging
  const int xkk = (tid >> 6) * 8;      // 4 wave-groups cover k-offsets 0,8,16,24
  const int vn  = tid & 127;           // node for V staging
  const int vkk = (tid >> 7) * 16;     // 2 half-grids cover k-offsets 0,16
  const bool vok = (n0 + vn < N_NODES);
  const float* vrow = V + (size_t)(n0 + vn) * DIM + vkk;
  const float* xrow = X + xsl * DIM + xkk;

  float4 xr0, xr1, vr[4];
  // prefetch chunk 0
  xr0 = *(const float4*)(xrow + 0);
  xr1 = *(const float4*)(xrow + 4);
#pragma unroll
  for (int m = 0; m < 4; m++)
    vr[m] = vok ? *(const float4*)(vrow + 4 * m) : make_float4(0.f, 0.f, 0.f, 0.f);

  for (int c = 0; c < 8; c++) {
    __syncthreads();
    // stage regs -> LDS (X transposed k-major; V half-chunk per thread)
    Xl[xkk + 0][xsl] = xr0.x; Xl[xkk + 1][xsl] = xr0.y;
    Xl[xkk + 2][xsl] = xr0.z; Xl[xkk + 3][xsl] = xr0.w;
    Xl[xkk + 4][xsl] = xr1.x; Xl[xkk + 5][xsl] = xr1.y;
    Xl[xkk + 6][xsl] = xr1.z; Xl[xkk + 7][xsl] = xr1.w;
#pragma unroll
    for (int m = 0; m < 4; m++) {
      Vl[vkk + 4 * m + 0][vn] = vr[m].x; Vl[vkk + 4 * m + 1][vn] = vr[m].y;
      Vl[vkk + 4 * m + 2][vn] = vr[m].z; Vl[vkk + 4 * m + 3][vn] = vr[m].w;
    }
    __syncthreads();
    // prefetch next chunk (latency hides under qa + FMA below)
    if (c + 1 < 8) {
      int kc = (c + 1) * KC;
      xr0 = *(const float4*)(xrow + kc);
      xr1 = *(const float4*)(xrow + kc + 4);
#pragma unroll
      for (int m = 0; m < 4; m++)
        vr[m] = vok ? *(const float4*)(vrow + kc + 4 * m)
                    : make_float4(0.f, 0.f, 0.f, 0.f);
    }
    // ||v||^2 chunk partial — node n0+tid, k ascending (bitwise chain of R5)
    if (tid < 128) {
      float qq = 0.f;
#pragma unroll 8
      for (int k = 0; k < KC; k++) { float t = Vl[k][tid]; qq += t * t; }
      qa += qq;
    }
    // 8x4 register-tile FMA, k ascending (per-element chains bitwise preserved)
#pragma unroll 4
    for (int k = 0; k < KC; k++) {
      float xs[8], vs[4];
      *(float4*)&xs[0] = *(const float4*)&Xl[k][ty * 8];      // broadcast (free)
      *(float4*)&xs[4] = *(const float4*)&Xl[k][ty * 8 + 4];  // broadcast (free)
      *(float4*)&vs[0] = *(const float4*)&Vl[k][tx * 4];      // stride-4: bank-optimal
#pragma unroll
      for (int i = 0; i < 8; i++)
#pragma unroll
        for (int u = 0; u < 4; u++) acc[i][u] += xs[i] * vs[u];
    }
  }
  if (tid < 128) sq[tid] = qa;
  __syncthreads();
  if (tid < 128 && n0 + tid < N_NODES) Q[n0 + tid] = qa;
  float qs[4];
  *(float4*)&qs[0] = *(const float4*)&sq[tx * 4];
  const bool full = (n0 + 128) <= N_NODES;
#pragma unroll
  for (int i = 0; i < 8; i++) {
    int s = ty * 8 + i;
    float xn = XX[s * NS + s];
#pragma unroll
    for (int u = 0; u < 4; u++) acc[i][u] = xn - 2.f * acc[i][u] + qs[u];
    float* prow = P + (size_t)s * N_NODES + n0 + tx * 4;
    if (full) {
      *(float4*)(prow) = make_float4(acc[i][0], acc[i][1], acc[i][2], acc[i][3]);
    } else {
#pragma unroll
      for (int u = 0; u < 4; u++) {
        int n = n0 + tx * 4 + u;
        if (n < N_NODES) prow[u] = acc[i][u];
      }
    }
  }
#pragma unroll
  for (int u = 0; u < 4; u++) {
    int n = n0 + tx * 4 + u;
    if (n < N_NODES) {
      float* pt = PT + (size_t)n * NS + ty * 8;
      *(float4*)(pt)     = make_float4(acc[0][u], acc[1][u], acc[2][u], acc[3][u]);
      *(float4*)(pt + 4) = make_float4(acc[4][u], acc[5][u], acc[6][u], acc[7][u]);
    }
  }
  // fused per-chunk(64) min: 16 tx-lanes per chunk (verified R5 form)
#pragma unroll
  for (int i = 0; i < 8; i++) {
    int s = ty * 8 + i;
    u64 key = ~0ull;
#pragma unroll
    for (int u = 0; u < 4; u++) {
      int n = n0 + tx * 4 + u;
      if (n < N_NODES) key = umin64(key, pk(acc[i][u], n));
    }
#pragma unroll
    for (int off = 1; off <= 8; off <<= 1)
      key = umin64(key, (u64)__shfl_xor((unsigned long long)key, off, 64));
    if ((tx & 15) == 0) {
      int chunk = (n0 >> 6) + (tx >> 4);
      if (chunk < NCH) SUMC[(size_t)s * NCH + chunk] = key;
    }
  }
}

// fused threshold + collect + sort: one block per sample
__global__ __launch_bounds__(1024) void k_build(const u64* __restrict__ SUMC,
                                                const float* __restrict__ P,
                                                u64* __restrict__ L) {
  __shared__ u64 A[CAP];            // 32 KB
  __shared__ u64 Twave[16];
  __shared__ float Tsh;
  __shared__ int cnt;
  const int j = blockIdx.x, tid = threadIdx.x;
  const int w = tid >> 6, l = tid & 63;
  // phase 1: per-wave 9th-smallest chunk-min; T = max over waves.
  {
    int base = w * 98;
    u64 v0 = (base + l < NCH) ? SUMC[(size_t)j * NCH + base + l] : ~0ull;
    u64 v1 = (l < 34 && base + 64 + l < NCH)
                 ? SUMC[(size_t)j * NCH + base + 64 + l] : ~0ull;
    u64 s9 = ~0ull;
#pragma unroll
    for (int r = 0; r < 9; r++) {
      u64 m = umin64(v0, v1);
#pragma unroll
      for (int off = 1; off <= 32; off <<= 1)
        m = umin64(m, (u64)__shfl_xor((unsigned long long)m, off, 64));
      if (r == 8) { s9 = m; } else {
        if (v0 == m) v0 = ~0ull;
        if (v1 == m) v1 = ~0ull;
      }
    }
    if (l == 0) Twave[w] = s9;
  }
  __syncthreads();
  if (tid == 0) {
    u64 t = 0;
    for (int i = 0; i < 16; i++) t = umax64(t, Twave[i]);
    Tsh = __uint_as_float((unsigned)(t >> 32));   // >=144 entries <= T guaranteed
    cnt = 0;
  }
  __syncthreads();
  const float T = Tsh;
  // phase 2: compact candidates (d <= T) into A
  const float* prow = P + (size_t)j * N_NODES;
  for (int n0 = tid * 4; n0 < N_NODES + 3; n0 += 4096) {
    float d[4];
    if (n0 + 3 < N_NODES) {
      float4 p = *(const float4*)(prow + n0);
      d[0] = p.x; d[1] = p.y; d[2] = p.z; d[3] = p.w;
    } else {
#pragma unroll
      for (int e = 0; e < 4; e++)
        d[e] = (n0 + e < N_NODES) ? prow[n0 + e] : INFINITY;
    }
#pragma unroll
    for (int e = 0; e < 4; e++) {
      if (d[e] <= T) {
        int pos = atomicAdd(&cnt, 1);
        if (pos < CAP) A[pos] = pk(d[e], n0 + e);
      }
    }
  }
  __syncthreads();
  int n = cnt; if (n > CAP) n = CAP;
  int M = 256; while (M < n) M <<= 1;
  for (int i = tid; i < M; i += 1024)
    if (i >= n) A[i] = ~0ull;
  __syncthreads();
  // phase 3: bitonic sort M
  for (int k = 2; k <= M; k <<= 1)
    for (int s2 = k >> 1; s2 > 0; s2 >>= 1) {
      for (int i = tid; i < M; i += 1024) {
        int p = i ^ s2;
        if (p > i) {
          u64 a = A[i], b = A[p];
          bool up = ((i & k) == 0);
          if ((a > b) == up) { A[i] = b; A[p] = a; }
        }
      }
      __syncthreads();
    }
  for (int i = tid; i < KLS; i += 1024) L[(size_t)j * KL + i] = A[i];
}

__global__ __launch_bounds__(320) void k_seq(
    const float* __restrict__ PT, const float* __restrict__ Q,
    const float* __restrict__ XXg, const u64* __restrict__ L,
    const int* __restrict__ itp, float* __restrict__ out) {
  __shared__ float XXl[NS * 65];         // 16640
  __shared__ float g[128][65];           // 33280
  __shared__ float qv[128];
  __shared__ unsigned int bitmap[NBMW];  // 12500 (consumer writes, producers read)
  __shared__ int tracked[128];
  __shared__ u64 cand16[NS][16];         // 8192: first-16-untracked, rank-tagged
  __shared__ float specg[8][12][NS];     // 24576: PT rows of first-12-untracked
  __shared__ float specq[8][12];
  __shared__ int readyS[NS];             // cand16[t] AND specs complete
  __shared__ int done[NS];

  const int tid = threadIdx.x;           // 320 = 5 waves (1 consumer + 4 producers)
  const int wv = tid >> 6;
  const int lane = tid & 63;

  for (int i = tid; i < NS * NS; i += 320) {
    int r = i >> 6, c = i & 63;
    XXl[r * 65 + c] = XXg[i];
  }
  for (int i = tid; i < NBMW; i += 320) bitmap[i] = 0u;
  for (int i = tid; i < NS; i += 320) { readyS[i] = 0; done[i] = 0; }
  __syncthreads();

  const int it = itp[0];
  const float eps_b = 1.0f / (float)(it + 2);
  const float eps_n = 1.0f / (float)((it + 1) * 100);
  const float xdl = XXl[lane * 65 + lane];

  if (wv == 0) {
    // ========== consumer: one spin/step, batched LDS reads (R12 form) ========
    int ns = 0;
    int pw[8];                            // winners of steps j-1..j-4
#pragma unroll
    for (int k2 = 0; k2 < 8; k2++) pw[k2] = -1;
    // prologue: step-0 batch (readyS implies cand16 complete)
    SPIN(readyS[0]);
    u64 ck = (lane < 16) ? cand16[0][lane] : ~0ull;
    float gA = g[lane][0], gB = g[lane + 64][0];   // garbage until tracked (unused)
    float qvA = qv[lane], qvB = qv[lane + 64];     // garbage until tracked (unused)
    int tA = tracked[lane], tB = tracked[lane + 64];
    float xrow = XXl[0 * 65 + lane];

    for (int j = 0; j < NS; j++) {
      const float xnj = rdlane_f(xdl, j);          // == XXl[j*65+j]
      // keys: candidate (patched vs last-8 winners) + tracked distances
      u64 A0 = ~0ull, A1 = ~0ull;
      {
        int id = (int)((unsigned)ck & 0x1FFFFu);
        bool ok = (ck != ~0ull);
#pragma unroll
        for (int k2 = 0; k2 < 8; k2++) ok = ok && (id != pw[k2]);
        if (ok) A0 = ck;
      }
      if (lane < ns)      { float d = xnj - 2.f * gA + qvA; mrg2(A0, A1, tkey(d, lane, tA), ~0ull); }
      if (lane + 64 < ns) { float d = xnj - 2.f * gB + qvB; mrg2(A0, A1, tkey(d, lane + 64, tB), ~0ull); }
      // DPP min-2 -> exact top-2 in lane 63
      dpp_round<0x111>(A0, A1);
      dpp_round<0x112>(A0, A1);
      dpp_round<0x114>(A0, A1);
      dpp_round<0x118>(A0, A1);
      dpp_round<0x142>(A0, A1);
      dpp_round<0x143>(A0, A1);
      const unsigned lo0 = (unsigned)__builtin_amdgcn_readlane(
          (int)(unsigned)(A0 & 0xFFFFFFFFull), 63);
      const unsigned lo1 = (unsigned)__builtin_amdgcn_readlane(
          (int)(unsigned)(A1 & 0xFFFFFFFFull), 63);
      const int r0 = (int)(lo0 & 0x1FFFFu);
      const int r1 = (int)(lo1 & 0x1FFFFu);
      const bool new0 = (lo0 & 0x80000000u) == 0u;
      const bool new1 = (lo1 & 0x80000000u) == 0u;
      const int sl0 = new0 ? ns : (int)((lo0 >> 17) & 127u);
      const int sl1 = new1 ? (ns + (new0 ? 1 : 0)) : (int)((lo1 >> 17) & 127u);
      const int rk0 = (int)((lo0 >> 17) & 15u);   // valid iff new0
      const int rk1 = (int)((lo1 >> 17) & 15u);   // valid iff new1

      // issue row-state + rank-indexed spec reads
      const int sb = j & 7;
      float gt0 = g[sl0][lane];
      float gt1 = g[sl1][lane];
      float pv0 = 0.f, qq0 = 0.f, pv1 = 0.f, qq1 = 0.f;
      if (new0) { pv0 = specg[sb][rk0][lane]; qq0 = specq[sb][rk0]; }
      if (new1) { pv1 = specg[sb][rk1][lane]; qq1 = specq[sb][rk1]; }

      // bitmap + early done release (producers need only bitmap+done);
      // the release's lgkm drain doubles as the wait for the reads above.
      if (lane == 0) {
        if (new0) bitmap[r0 >> 5] |= 1u << (r0 & 31);
        if (new1) bitmap[r1 >> 5] |= 1u << (r1 & 31);
      }
      __hip_atomic_store(&done[j], 1, __ATOMIC_RELEASE,
                         __HIP_MEMORY_SCOPE_WORKGROUP);

      // output AFTER the release (keeps vmcnt out of the release drain)
      if (lane == 63) {
        float2 o;
        o.x = sqrtf(fmaxf(__uint_as_float((unsigned)(A0 >> 32)), 0.f) + 1e-12f);
        o.y = sqrtf(fmaxf(__uint_as_float((unsigned)(A1 >> 32)), 0.f) + 1e-12f);
        *(float2*)(out + j * 2) = o;
      }

      // safety fallback (provably never taken: rank <= 9 with patch-8)
      if (new0 && rk0 >= 12) { pv0 = PT[(size_t)r0 * NS + lane]; qq0 = Q[r0]; }
      if (new1 && rk1 >= 12) { pv1 = PT[(size_t)r1 * NS + lane]; qq1 = Q[r1]; }

      // updates — expressions bitwise identical to verified form
      float gold0 = new0 ? (0.5f * (xdl + qq0 - pv0)) : gt0;
      g[sl0][lane] = (1.f - eps_b) * gold0 + eps_b * xrow;
      float qold0 = new0 ? qq0 : rdlane_f(sl0 < 64 ? qvA : qvB, sl0 & 63);
      float gj0 = rdlane_f(gold0, j);
      if (lane == 0) {
        float om = 1.f - eps_b;
        qv[sl0] = om * om * qold0 + 2.f * eps_b * om * gj0 + eps_b * eps_b * xnj;
        tracked[sl0] = r0;
      }
      float gold1 = new1 ? (0.5f * (xdl + qq1 - pv1)) : gt1;
      g[sl1][lane] = (1.f - eps_n) * gold1 + eps_n * xrow;
      float qold1 = new1 ? qq1 : rdlane_f(sl1 < 64 ? qvA : qvB, sl1 & 63);
      float gj1 = rdlane_f(gold1, j);
      if (lane == 0) {
        float on = 1.f - eps_n;
        qv[sl1] = on * on * qold1 + 2.f * eps_n * on * gj1 + eps_n * eps_n * xnj;
        tracked[sl1] = r1;
      }
      ns += (new0 ? 1 : 0) + (new1 ? 1 : 0);
#pragma unroll
      for (int k2 = 7; k2 >= 2; k2--) pw[k2] = pw[k2 - 2];
      pw[0] = r0; pw[1] = r1;

      // end of step: single spin for next step, then batch prefetch
      // (reads issued after this step's g/qv/tracked writes -> correct values)
      if (j < 63) {
        SPIN(readyS[j + 1]);
        ck = (lane < 16) ? cand16[j + 1][lane] : ~0ull;
        gA = g[lane][j + 1]; gB = g[lane + 64][j + 1];
        qvA = qv[lane]; qvB = qv[lane + 64];
        tA = tracked[lane]; tB = tracked[lane + 64];
        xrow = XXl[(j + 1) * 65 + lane];
      }
    }
  } else {
    // ====== producers: waves 1..4 handle t == (wv-1) mod 4, wait done[t-5] ====
    for (int t = wv - 1; t < NS; t += 4) {
      // L is read-only: issue loads before the wait so latency hides under it.
      const u64* Lr = L + (size_t)t * KL;
      u64 e0 = Lr[lane], e1 = Lr[lane + 64];
      u64 e2 = (lane < 8) ? Lr[128 + lane] : ~0ull;
      if (t >= 5) { SPIN(done[t - 5]); }
      int i0 = (int)(unsigned)(e0 & 0xFFFFFFFFull);
      int i1 = (int)(unsigned)(e1 & 0xFFFFFFFFull);
      int i2 = (int)(unsigned)(e2 & 0xFFFFFFFFull);
      bool t0 = (e0 == ~0ull) || ((bitmap[i0 >> 5] >> (i0 & 31)) & 1u);
      bool t1 = (e1 == ~0ull) || ((bitmap[i1 >> 5] >> (i1 & 31)) & 1u);
      bool t2 = (e2 == ~0ull) || ((bitmap[i2 >> 5] >> (i2 & 31)) & 1u);
      u64 um0 = ~__ballot(t0), um1 = ~__ballot(t1), um2 = ~__ballot(t2);
      u64 below = (1ull << lane) - 1;
      int c0n = __popcll((unsigned long long)um0);
      int c1n = __popcll((unsigned long long)um1);
      int rank0 = __popcll((unsigned long long)(um0 & below));
      int rank1 = c0n + __popcll((unsigned long long)(um1 & below));
      int rank2 = c0n + c1n + __popcll((unsigned long long)(um2 & below));
      // rank-tagged entries (node < 2^17; rank in bits 17..20; bit31 clear)
      if (!t0 && rank0 < 16) cand16[t][rank0] = e0 | ((u64)(unsigned)rank0 << 17);
      if (!t1 && rank1 < 16) cand16[t][rank1] = e1 | ((u64)(unsigned)rank1 << 17);
      if (!t2 && rank2 < 16) cand16[t][rank2] = e2 | ((u64)(unsigned)rank2 << 17);
      int U = c0n + c1n + __popcll((unsigned long long)um2);
      if (lane < 16 && lane >= U) cand16[t][lane] = ~0ull;
      // spec: first-12-untracked PT/Q, rank-indexed (U >= 10 guaranteed;
      // entries >= U read row 0 as dummy — winner rank <= 9 is always spec'd)
      const int sb = t & 7;
      int ids[12];
#pragma unroll
      for (int s = 0; s < 12; s++) {
        u64 e = cand16[t][s];
        ids[s] = (e == ~0ull) ? 0 : (int)((unsigned)e & 0x1FFFFu);
      }
#pragma unroll
      for (int s = 0; s < 12; s++)
        specg[sb][s][lane] = PT[(size_t)ids[s] * NS + lane];
      if (lane < 12) specq[sb][lane] = Q[ids[lane]];
      // single release: cand16 + specs all visible before readyS
      __hip_atomic_store(&readyS[t], 1, __ATOMIC_RELEASE,
                         __HIP_MEMORY_SCOPE_WORKGROUP);
    }
  }
}

extern "C" void kernel_launch(void* const* d_in, const int* in_sizes, int n_in,
                              void* d_out, int out_size, void* d_ws, size_t ws_size,
                              hipStream_t stream) {
  const float* X  = (const float*)d_in[0];  // [64,256]
  const float* V  = (const float*)d_in[1];  // [100000,256]
  const int*  itp = (const int*)d_in[3];    // scalar it
  float* out = (float*)d_out;               // [64,2]

  char* ws = (char*)d_ws;
  size_t off = 0;
  auto alloc = [&](size_t bytes) -> void* {
    size_t o = (off + 255) & ~(size_t)255;
    off = o + bytes;
    return (void*)(ws + o);
  };
  float* P    = (float*)alloc((size_t)NS * N_NODES * sizeof(float)); // 25.6 MB
  float* PT   = (float*)alloc((size_t)NS * N_NODES * sizeof(float)); // 25.6 MB
  float* Q    = (float*)alloc((size_t)N_NODES * sizeof(float));
  float* XXp  = (float*)alloc((size_t)NS * NS * sizeof(float));
  u64*   SUMC = (u64*)alloc((size_t)NS * NCH * sizeof(u64));         // 800 KB
  u64*   Lst  = (u64*)alloc((size_t)NS * KL * sizeof(u64));          // 96 KB

  k_xx   <<<NS, NS, 0, stream>>>(X, XXp);
  k_dist <<<(N_NODES + 127) / 128, 256, 0, stream>>>(X, V, XXp, P, PT, Q, SUMC);
  k_build<<<NS, 1024, 0, stream>>>(SUMC, P, Lst);
  k_seq  <<<1, 320, 0, stream>>>(PT, Q, XXp, Lst, itp, out);
}

// Round 7
// 308.324 us; speedup vs baseline: 1.0076x; 1.0076x over previous
//
#include <hip/hip_runtime.h>
#include <math.h>

// SOINN+ restructured, round 14 (resubmit — R6 bench was an infra timeout):
//  k_xx    : unchanged.
//  k_dist  : inner FMA tile switched to v_pk_fma_f32 (VOP3P packed dual fp32
//            FMA): 16 pk-FMAs/k instead of 32 v_fmac_f32 -> halves the
//            dominant VALU issue stream. Per-element accumulation chains are
//            bit-identical (same fused FMA, same k order); op_sel broadcasts
//            the X scalar so no extra moves. Staging/qa/epilogue untouched.
//  k_build : unchanged from round 8.
//  k_seq   : reverted EXACTLY to the R10 form (best measured: 81.4us).
//            R11/R12/R13 consumer variants all measured slower; the
//            prefetch-then-select structure with two flags and late done
//            release is the verified local optimum.

#define N_NODES 100000
#define DIM     256
#define NS      64
#define NCH     1563
#define KC      32
#define NBMW    3125
#define CAP     4096
#define KL      192
#define KLS     136

typedef unsigned long long u64;
typedef __attribute__((ext_vector_type(2))) float f32x2;

__device__ __forceinline__ u64 pk(float d, int i) {
  return ((u64)__float_as_uint(d) << 32) | (unsigned)i;
}
// tracked-provenance key: bit31 flag, slot<<17 (slot<128), node in low 17 bits
__device__ __forceinline__ u64 tkey(float d, int slot, int node) {
  return ((u64)__float_as_uint(d) << 32) |
         (u64)(0x80000000u | ((unsigned)slot << 17) | (unsigned)node);
}
__device__ __forceinline__ u64 umin64(u64 a, u64 b) { return a < b ? a : b; }
__device__ __forceinline__ u64 umax64(u64 a, u64 b) { return a > b ? a : b; }
__device__ __forceinline__ void mrg2(u64& A0, u64& A1, u64 B0, u64 B1) {
  u64 m = umax64(A0, B0);
  A0 = umin64(A0, B0);
  A1 = umin64(umin64(A1, B1), m);
}

// packed dual FMA: acc.lo += x.sel * v.lo ; acc.hi += x.sel * v.hi
// _lo: broadcast word0 of xpair; _hi: broadcast word1.
__device__ __forceinline__ void pkfma_lo(f32x2& acc, f32x2 xp, f32x2 vp) {
  asm("v_pk_fma_f32 %0, %1, %2, %0 op_sel:[0,0,0] op_sel_hi:[0,1,1]"
      : "+v"(acc) : "v"(xp), "v"(vp));
}
__device__ __forceinline__ void pkfma_hi(f32x2& acc, f32x2 xp, f32x2 vp) {
  asm("v_pk_fma_f32 %0, %1, %2, %0 op_sel:[1,0,0] op_sel_hi:[1,1,1]"
      : "+v"(acc) : "v"(xp), "v"(vp));
}

template <int C>
__device__ __forceinline__ u64 dpp64(u64 x) {
  unsigned lo = (unsigned)__builtin_amdgcn_update_dpp(
      (int)0xFFFFFFFF, (int)(unsigned)(x & 0xFFFFFFFFull), C, 0xF, 0xF, false);
  unsigned hi = (unsigned)__builtin_amdgcn_update_dpp(
      (int)0xFFFFFFFF, (int)(unsigned)(x >> 32), C, 0xF, 0xF, false);
  return ((u64)hi << 32) | lo;
}
template <int C>
__device__ __forceinline__ void dpp_round(u64& A0, u64& A1) {
  u64 B0 = dpp64<C>(A0);
  u64 B1 = dpp64<C>(A1);
  mrg2(A0, A1, B0, B1);
}

__global__ void k_xx(const float* __restrict__ X, float* __restrict__ XX) {
  int i = blockIdx.x, j = threadIdx.x;
  const float* xi = X + i * DIM;
  const float* xj = X + j * DIM;
  float acc = 0.f;
  for (int k = 0; k < DIM; k += 4) {
    float4 a = *(const float4*)(xi + k);
    float4 b = *(const float4*)(xj + k);
    acc += a.x * b.x + a.y * b.y + a.z * b.z + a.w * b.w;
  }
  XX[i * NS + j] = acc;
}

__global__ __launch_bounds__(256) void k_dist(const float* __restrict__ X,
                                              const float* __restrict__ V,
                                              const float* __restrict__ XX,
                                              float* __restrict__ P,
                                              float* __restrict__ PT,
                                              float* __restrict__ Q,
                                              u64* __restrict__ SUMC) {
  __shared__ float Xl[KC][68];     // 64 samples, k-major
  __shared__ float Vl[KC][132];    // 128 nodes, k-major (+4 pad; rows 16B-aligned)
  __shared__ float sq[128];
  const int tid = threadIdx.x;     // 256 threads
  const int n0  = blockIdx.x * 128;
  const int ty  = tid >> 5;        // 0..7  -> samples 8ty..8ty+7
  const int tx  = tid & 31;        // 0..31 -> nodes 4tx..4tx+3 (stride-4: bank-optimal)
  f32x2 acc2[8][2];                // acc2[i][j] = {acc[i][2j], acc[i][2j+1]}
#pragma unroll
  for (int i = 0; i < 8; i++)
#pragma unroll
    for (int j = 0; j < 2; j++) { acc2[i][j][0] = 0.f; acc2[i][j][1] = 0.f; }
  float qa = 0.f;
  const int xsl = tid & 63;            // sample row for X staging
  const int xkk = (tid >> 6) * 8;      // 4 wave-groups cover k-offsets 0,8,16,24
  const int vn  = tid & 127;           // node for V staging
  const int vkk = (tid >> 7) * 16;     // 2 half-grids cover k-offsets 0,16
  const bool vok = (n0 + vn < N_NODES);
  const float* vrow = V + (size_t)(n0 + vn) * DIM + vkk;
  const float* xrow = X + xsl * DIM + xkk;

  float4 xr0, xr1, vr[4];
  // prefetch chunk 0
  xr0 = *(const float4*)(xrow + 0);
  xr1 = *(const float4*)(xrow + 4);
#pragma unroll
  for (int m = 0; m < 4; m++)
    vr[m] = vok ? *(const float4*)(vrow + 4 * m) : make_float4(0.f, 0.f, 0.f, 0.f);

  for (int c = 0; c < 8; c++) {
    __syncthreads();
    // stage regs -> LDS (X transposed k-major; V half-chunk per thread)
    Xl[xkk + 0][xsl] = xr0.x; Xl[xkk + 1][xsl] = xr0.y;
    Xl[xkk + 2][xsl] = xr0.z; Xl[xkk + 3][xsl] = xr0.w;
    Xl[xkk + 4][xsl] = xr1.x; Xl[xkk + 5][xsl] = xr1.y;
    Xl[xkk + 6][xsl] = xr1.z; Xl[xkk + 7][xsl] = xr1.w;
#pragma unroll
    for (int m = 0; m < 4; m++) {
      Vl[vkk + 4 * m + 0][vn] = vr[m].x; Vl[vkk + 4 * m + 1][vn] = vr[m].y;
      Vl[vkk + 4 * m + 2][vn] = vr[m].z; Vl[vkk + 4 * m + 3][vn] = vr[m].w;
    }
    __syncthreads();
    // prefetch next chunk (latency hides under qa + FMA below)
    if (c + 1 < 8) {
      int kc = (c + 1) * KC;
      xr0 = *(const float4*)(xrow + kc);
      xr1 = *(const float4*)(xrow + kc + 4);
#pragma unroll
      for (int m = 0; m < 4; m++)
        vr[m] = vok ? *(const float4*)(vrow + kc + 4 * m)
                    : make_float4(0.f, 0.f, 0.f, 0.f);
    }
    // ||v||^2 chunk partial — node n0+tid, k ascending (bitwise chain of R5)
    if (tid < 128) {
      float qq = 0.f;
#pragma unroll 8
      for (int k = 0; k < KC; k++) { float t = Vl[k][tid]; qq += t * t; }
      qa += qq;
    }
    // 8x4 register-tile FMA, k ascending, packed dual-FMA form.
    // acc2[i][j] chains are the exact per-element chains of acc[i][u]
    // (v_pk_fma_f32 = two independent fused FMAs; same op, same order).
#pragma unroll 4
    for (int k = 0; k < KC; k++) {
      float4 xa = *(const float4*)&Xl[k][ty * 8];      // broadcast (free)
      float4 xb = *(const float4*)&Xl[k][ty * 8 + 4];  // broadcast (free)
      float4 vv = *(const float4*)&Vl[k][tx * 4];      // stride-4: bank-optimal
      f32x2 xp0, xp1, xp2, xp3, vp0, vp1;
      xp0[0] = xa.x; xp0[1] = xa.y;
      xp1[0] = xa.z; xp1[1] = xa.w;
      xp2[0] = xb.x; xp2[1] = xb.y;
      xp3[0] = xb.z; xp3[1] = xb.w;
      vp0[0] = vv.x; vp0[1] = vv.y;
      vp1[0] = vv.z; vp1[1] = vv.w;
      pkfma_lo(acc2[0][0], xp0, vp0); pkfma_lo(acc2[0][1], xp0, vp1);
      pkfma_hi(acc2[1][0], xp0, vp0); pkfma_hi(acc2[1][1], xp0, vp1);
      pkfma_lo(acc2[2][0], xp1, vp0); pkfma_lo(acc2[2][1], xp1, vp1);
      pkfma_hi(acc2[3][0], xp1, vp0); pkfma_hi(acc2[3][1], xp1, vp1);
      pkfma_lo(acc2[4][0], xp2, vp0); pkfma_lo(acc2[4][1], xp2, vp1);
      pkfma_hi(acc2[5][0], xp2, vp0); pkfma_hi(acc2[5][1], xp2, vp1);
      pkfma_lo(acc2[6][0], xp3, vp0); pkfma_lo(acc2[6][1], xp3, vp1);
      pkfma_hi(acc2[7][0], xp3, vp0); pkfma_hi(acc2[7][1], xp3, vp1);
    }
  }
  // unpack to the scalar view used by the (unchanged) epilogue
  float acc[8][4];
#pragma unroll
  for (int i = 0; i < 8; i++)
#pragma unroll
    for (int j = 0; j < 2; j++) {
      acc[i][2 * j]     = acc2[i][j][0];
      acc[i][2 * j + 1] = acc2[i][j][1];
    }
  if (tid < 128) sq[tid] = qa;
  __syncthreads();
  if (tid < 128 && n0 + tid < N_NODES) Q[n0 + tid] = qa;
  float qs[4];
  *(float4*)&qs[0] = *(const float4*)&sq[tx * 4];
  const bool full = (n0 + 128) <= N_NODES;
#pragma unroll
  for (int i = 0; i < 8; i++) {
    int s = ty * 8 + i;
    float xn = XX[s * NS + s];
#pragma unroll
    for (int u = 0; u < 4; u++) acc[i][u] = xn - 2.f * acc[i][u] + qs[u];
    float* prow = P + (size_t)s * N_NODES + n0 + tx * 4;
    if (full) {
      *(float4*)(prow) = make_float4(acc[i][0], acc[i][1], acc[i][2], acc[i][3]);
    } else {
#pragma unroll
      for (int u = 0; u < 4; u++) {
        int n = n0 + tx * 4 + u;
        if (n < N_NODES) prow[u] = acc[i][u];
      }
    }
  }
#pragma unroll
  for (int u = 0; u < 4; u++) {
    int n = n0 + tx * 4 + u;
    if (n < N_NODES) {
      float* pt = PT + (size_t)n * NS + ty * 8;
      *(float4*)(pt)     = make_float4(acc[0][u], acc[1][u], acc[2][u], acc[3][u]);
      *(float4*)(pt + 4) = make_float4(acc[4][u], acc[5][u], acc[6][u], acc[7][u]);
    }
  }
  // fused per-chunk(64) min: 16 tx-lanes per chunk (verified R5 form)
#pragma unroll
  for (int i = 0; i < 8; i++) {
    int s = ty * 8 + i;
    u64 key = ~0ull;
#pragma unroll
    for (int u = 0; u < 4; u++) {
      int n = n0 + tx * 4 + u;
      if (n < N_NODES) key = umin64(key, pk(acc[i][u], n));
    }
#pragma unroll
    for (int off = 1; off <= 8; off <<= 1)
      key = umin64(key, (u64)__shfl_xor((unsigned long long)key, off, 64));
    if ((tx & 15) == 0) {
      int chunk = (n0 >> 6) + (tx >> 4);
      if (chunk < NCH) SUMC[(size_t)s * NCH + chunk] = key;
    }
  }
}

// fused threshold + collect + sort: one block per sample
__global__ __launch_bounds__(1024) void k_build(const u64* __restrict__ SUMC,
                                                const float* __restrict__ P,
                                                u64* __restrict__ L) {
  __shared__ u64 A[CAP];            // 32 KB
  __shared__ u64 Twave[16];
  __shared__ float Tsh;
  __shared__ int cnt;
  const int j = blockIdx.x, tid = threadIdx.x;
  const int w = tid >> 6, l = tid & 63;
  // phase 1: per-wave 9th-smallest chunk-min; T = max over waves.
  {
    int base = w * 98;
    u64 v0 = (base + l < NCH) ? SUMC[(size_t)j * NCH + base + l] : ~0ull;
    u64 v1 = (l < 34 && base + 64 + l < NCH)
                 ? SUMC[(size_t)j * NCH + base + 64 + l] : ~0ull;
    u64 s9 = ~0ull;
#pragma unroll
    for (int r = 0; r < 9; r++) {
      u64 m = umin64(v0, v1);
#pragma unroll
      for (int off = 1; off <= 32; off <<= 1)
        m = umin64(m, (u64)__shfl_xor((unsigned long long)m, off, 64));
      if (r == 8) { s9 = m; } else {
        if (v0 == m) v0 = ~0ull;
        if (v1 == m) v1 = ~0ull;
      }
    }
    if (l == 0) Twave[w] = s9;
  }
  __syncthreads();
  if (tid == 0) {
    u64 t = 0;
    for (int i = 0; i < 16; i++) t = umax64(t, Twave[i]);
    Tsh = __uint_as_float((unsigned)(t >> 32));   // >=144 entries <= T guaranteed
    cnt = 0;
  }
  __syncthreads();
  const float T = Tsh;
  // phase 2: compact candidates (d <= T) into A
  const float* prow = P + (size_t)j * N_NODES;
  for (int n0 = tid * 4; n0 < N_NODES + 3; n0 += 4096) {
    float d[4];
    if (n0 + 3 < N_NODES) {
      float4 p = *(const float4*)(prow + n0);
      d[0] = p.x; d[1] = p.y; d[2] = p.z; d[3] = p.w;
    } else {
#pragma unroll
      for (int e = 0; e < 4; e++)
        d[e] = (n0 + e < N_NODES) ? prow[n0 + e] : INFINITY;
    }
#pragma unroll
    for (int e = 0; e < 4; e++) {
      if (d[e] <= T) {
        int pos = atomicAdd(&cnt, 1);
        if (pos < CAP) A[pos] = pk(d[e], n0 + e);
      }
    }
  }
  __syncthreads();
  int n = cnt; if (n > CAP) n = CAP;
  int M = 256; while (M < n) M <<= 1;
  for (int i = tid; i < M; i += 1024)
    if (i >= n) A[i] = ~0ull;
  __syncthreads();
  // phase 3: bitonic sort M
  for (int k = 2; k <= M; k <<= 1)
    for (int s2 = k >> 1; s2 > 0; s2 >>= 1) {
      for (int i = tid; i < M; i += 1024) {
        int p = i ^ s2;
        if (p > i) {
          u64 a = A[i], b = A[p];
          bool up = ((i & k) == 0);
          if ((a > b) == up) { A[i] = b; A[p] = a; }
        }
      }
      __syncthreads();
    }
  for (int i = tid; i < KLS; i += 1024) L[(size_t)j * KL + i] = A[i];
}

__global__ __launch_bounds__(192) void k_seq(
    const float* __restrict__ PT, const float* __restrict__ Q,
    const float* __restrict__ XXg, const u64* __restrict__ L,
    const int* __restrict__ itp, float* __restrict__ out) {
  __shared__ float XXl[NS * 65];         // 16640
  __shared__ float g[128][65];           // 33280
  __shared__ float qv[128];
  __shared__ unsigned int bitmap[NBMW];  // 12500 (wave0 writes, producers read)
  __shared__ int tracked[128];
  __shared__ u64 cand16[NS][16];         // 8192: first-16-untracked per step
  __shared__ float specg[4][6][NS];      // 6144: PT rows of first-6-untracked
  __shared__ float specq[4][6];
  __shared__ int   specid[4][6];
  __shared__ int readyC[NS];             // cand16[t] complete
  __shared__ int readyS[NS];             // specg/specq/specid[t&3] complete
  __shared__ int done[NS];

  const int tid = threadIdx.x;           // 192 = 3 waves
  const int wv = tid >> 6;
  const int lane = tid & 63;

  for (int i = tid; i < NS * NS; i += 192) {
    int r = i >> 6, c = i & 63;
    XXl[r * 65 + c] = XXg[i];
  }
  for (int i = tid; i < NBMW; i += 192) bitmap[i] = 0u;
  for (int i = tid; i < NS; i += 192) { readyC[i] = 0; readyS[i] = 0; done[i] = 0; }
  __syncthreads();

  const int it = itp[0];
  const float eps_b = 1.0f / (float)(it + 2);
  const float eps_n = 1.0f / (float)((it + 1) * 100);
  const float xdl = XXl[lane * 65 + lane];

  if (wv == 0) {
    // ================= consumer: pure LDS + VALU =================
    int ns = 0;
    int pw0 = -1, pw1 = -1, pw2 = -1, pw3 = -1;   // winners of steps j-1, j-2
    for (int j = 0; j < NS; j++) {
      while (__hip_atomic_load(&readyC[j], __ATOMIC_ACQUIRE,
                               __HIP_MEMORY_SCOPE_WORKGROUP) == 0)
        __builtin_amdgcn_s_sleep(1);
      const int sb = j & 3;
      u64 ck = (lane < 16) ? cand16[j][lane] : ~0ull;
      float gA = g[lane][j], gB = g[lane + 64][j];
      float qvA = qv[lane],  qvB = qv[lane + 64];
      int   tA = tracked[lane], tB = tracked[lane + 64];
      float xrow = XXl[j * 65 + lane];
      float xnj  = XXl[j * 65 + j];
      // candidates: compacted untracked list entry (patched vs last-4 winners)
      u64 A0 = ~0ull, A1 = ~0ull;
      {
        int id = (int)(unsigned)(ck & 0xFFFFFFFFull);
        bool ok = (ck != ~0ull) && id != pw0 && id != pw1 && id != pw2 && id != pw3;
        if (ok) { A0 = ck; }
      }
      // tracked algebraic distances (expression preserved; keys carry slot tag)
      if (lane < ns)      { float d = xnj - 2.f * gA + qvA; mrg2(A0, A1, tkey(d, lane, tA), ~0ull); }
      if (lane + 64 < ns) { float d = xnj - 2.f * gB + qvB; mrg2(A0, A1, tkey(d, lane + 64, tB), ~0ull); }
      // DPP min-2 -> exact top-2 in lane 63
      dpp_round<0x111>(A0, A1);
      dpp_round<0x112>(A0, A1);
      dpp_round<0x114>(A0, A1);
      dpp_round<0x118>(A0, A1);
      dpp_round<0x142>(A0, A1);
      dpp_round<0x143>(A0, A1);
      const unsigned lo0 = (unsigned)__builtin_amdgcn_readlane(
          (int)(unsigned)(A0 & 0xFFFFFFFFull), 63);
      const unsigned lo1 = (unsigned)__builtin_amdgcn_readlane(
          (int)(unsigned)(A1 & 0xFFFFFFFFull), 63);
      const int r0 = (int)(lo0 & 0x1FFFFu);
      const int r1 = (int)(lo1 & 0x1FFFFu);
      const bool new0 = (lo0 & 0x80000000u) == 0u;
      const bool new1 = (lo1 & 0x80000000u) == 0u;
      const int sl0 = new0 ? ns : (int)((lo0 >> 17) & 127u);
      const int sl1 = new1 ? (ns + (new0 ? 1 : 0)) : (int)((lo1 >> 17) & 127u);
      if (lane == 63) {
        float2 o;
        o.x = sqrtf(fmaxf(__uint_as_float((unsigned)(A0 >> 32)), 0.f) + 1e-12f);
        o.y = sqrtf(fmaxf(__uint_as_float((unsigned)(A1 >> 32)), 0.f) + 1e-12f);
        *(float2*)(out + j * 2) = o;
      }
      // issue slot-dependent LDS reads before the spec wait (overlap latency)
      float gt0 = g[sl0][lane];
      float gt1 = g[sl1][lane];
      // wait for specs only now — producer PT gather overlapped with reduce above
      while (__hip_atomic_load(&readyS[j], __ATOMIC_ACQUIRE,
                               __HIP_MEMORY_SCOPE_WORKGROUP) == 0)
        __builtin_amdgcn_s_sleep(1);
      float sgv[6], sqv[6]; int sid[6];
#pragma unroll
      for (int s = 0; s < 6; s++) {
        sgv[s] = specg[sb][s][lane];
        sid[s] = specid[sb][s];
        sqv[s] = specq[sb][s];
      }
      // spec select over 6 (values bitwise identical to direct loads)
      bool hit0 = false, hit1 = false;
      float pv0 = 0.f, qq0 = 0.f, pv1 = 0.f, qq1 = 0.f;
#pragma unroll
      for (int s = 0; s < 6; s++) {
        bool h0 = (sid[s] == r0), h1 = (sid[s] == r1);
        pv0 = h0 ? sgv[s] : pv0;  qq0 = h0 ? sqv[s] : qq0;  hit0 |= h0;
        pv1 = h1 ? sgv[s] : pv1;  qq1 = h1 ? sqv[s] : qq1;  hit1 |= h1;
      }
      if (new0 && !hit0) { pv0 = PT[(size_t)r0 * NS + lane]; qq0 = Q[r0]; } // never taken
      if (new1 && !hit1) { pv1 = PT[(size_t)r1 * NS + lane]; qq1 = Q[r1]; }
      // phase 0: r0 / eps_b
      float gold0 = new0 ? (0.5f * (xdl + qq0 - pv0)) : gt0;
      float qold0 = new0 ? qq0
                         : __uint_as_float((unsigned)__builtin_amdgcn_readlane(
                               (int)__float_as_uint(sl0 < 64 ? qvA : qvB), sl0 & 63));
      float gj0 = __uint_as_float(
          (unsigned)__builtin_amdgcn_readlane((int)__float_as_uint(gold0), j));
      g[sl0][lane] = (1.f - eps_b) * gold0 + eps_b * xrow;
      if (lane == 0) {
        float om = 1.f - eps_b;
        qv[sl0] = om * om * qold0 + 2.f * eps_b * om * gj0 + eps_b * eps_b * xnj;
        tracked[sl0] = r0;
        if (new0) bitmap[r0 >> 5] |= 1u << (r0 & 31);
      }
      // phase 1: r1 / eps_n
      float gold1 = new1 ? (0.5f * (xdl + qq1 - pv1)) : gt1;
      float qold1 = new1 ? qq1
                         : __uint_as_float((unsigned)__builtin_amdgcn_readlane(
                               (int)__float_as_uint(sl1 < 64 ? qvA : qvB), sl1 & 63));
      float gj1 = __uint_as_float(
          (unsigned)__builtin_amdgcn_readlane((int)__float_as_uint(gold1), j));
      g[sl1][lane] = (1.f - eps_n) * gold1 + eps_n * xrow;
      if (lane == 0) {
        float on = 1.f - eps_n;
        qv[sl1] = on * on * qold1 + 2.f * eps_n * on * gj1 + eps_n * eps_n * xnj;
        tracked[sl1] = r1;
        if (new1) bitmap[r1 >> 5] |= 1u << (r1 & 31);
      }
      ns += (new0 ? 1 : 0) + (new1 ? 1 : 0);
      pw2 = pw0; pw3 = pw1; pw0 = r0; pw1 = r1;
      __hip_atomic_store(&done[j], 1, __ATOMIC_RELEASE,
                         __HIP_MEMORY_SCOPE_WORKGROUP);
    }
  } else {
    // ========== producers (wv=1: even t, wv=2: odd t), wait done[t-3] ==========
    for (int t = (wv == 1 ? 0 : 1); t < NS; t += 2) {
      // L is read-only in this kernel: issue loads BEFORE the wait so their
      // latency hides under the spin.
      const u64* Lr = L + (size_t)t * KL;
      u64 e0 = Lr[lane], e1 = Lr[lane + 64];
      u64 e2 = (lane < 8) ? Lr[128 + lane] : ~0ull;
      if (t >= 3) {
        while (__hip_atomic_load(&done[t - 3], __ATOMIC_ACQUIRE,
                                 __HIP_MEMORY_SCOPE_WORKGROUP) == 0)
          __builtin_amdgcn_s_sleep(1);
      }
      int i0 = (int)(unsigned)(e0 & 0xFFFFFFFFull);
      int i1 = (int)(unsigned)(e1 & 0xFFFFFFFFull);
      int i2 = (int)(unsigned)(e2 & 0xFFFFFFFFull);
      bool t0 = (e0 == ~0ull) || ((bitmap[i0 >> 5] >> (i0 & 31)) & 1u);
      bool t1 = (e1 == ~0ull) || ((bitmap[i1 >> 5] >> (i1 & 31)) & 1u);
      bool t2 = (e2 == ~0ull) || ((bitmap[i2 >> 5] >> (i2 & 31)) & 1u);
      u64 um0 = ~__ballot(t0), um1 = ~__ballot(t1), um2 = ~__ballot(t2);
      u64 below = (1ull << lane) - 1;
      int c0n = __popcll((unsigned long long)um0);
      int c1n = __popcll((unsigned long long)um1);
      int rank0 = __popcll((unsigned long long)(um0 & below));
      int rank1 = c0n + __popcll((unsigned long long)(um1 & below));
      int rank2 = c0n + c1n + __popcll((unsigned long long)(um2 & below));
      if (!t0 && rank0 < 16) cand16[t][rank0] = e0;
      if (!t1 && rank1 < 16) cand16[t][rank1] = e1;
      if (!t2 && rank2 < 16) cand16[t][rank2] = e2;
      int U = c0n + c1n + __popcll((unsigned long long)um2);
      if (lane < 16 && lane >= U) cand16[t][lane] = ~0ull;
      // cand16 complete: release to consumer before the slow PT gather
      __hip_atomic_store(&readyC[t], 1, __ATOMIC_RELEASE,
                         __HIP_MEMORY_SCOPE_WORKGROUP);
      // spec: first-6-untracked PT/Q (U >= 136-126 = 10 >= 6 always)
      const int sb = t & 3;
      int ids[6];
#pragma unroll
      for (int s = 0; s < 6; s++)
        ids[s] = (int)(unsigned)(cand16[t][s] & 0xFFFFFFFFull);
#pragma unroll
      for (int s = 0; s < 6; s++)
        specg[sb][s][lane] = PT[(size_t)ids[s] * NS + lane];
      if (lane < 6) {
        specid[sb][lane] = ids[lane];
        specq[sb][lane] = Q[ids[lane]];
      }
      __hip_atomic_store(&readyS[t], 1, __ATOMIC_RELEASE,
                         __HIP_MEMORY_SCOPE_WORKGROUP);
    }
  }
}

extern "C" void kernel_launch(void* const* d_in, const int* in_sizes, int n_in,
                              void* d_out, int out_size, void* d_ws, size_t ws_size,
                              hipStream_t stream) {
  const float* X  = (const float*)d_in[0];  // [64,256]
  const float* V  = (const float*)d_in[1];  // [100000,256]
  const int*  itp = (const int*)d_in[3];    // scalar it
  float* out = (float*)d_out;               // [64,2]

  char* ws = (char*)d_ws;
  size_t off = 0;
  auto alloc = [&](size_t bytes) -> void* {
    size_t o = (off + 255) & ~(size_t)255;
    off = o + bytes;
    return (void*)(ws + o);
  };
  float* P    = (float*)alloc((size_t)NS * N_NODES * sizeof(float)); // 25.6 MB
  float* PT   = (float*)alloc((size_t)NS * N_NODES * sizeof(float)); // 25.6 MB
  float* Q    = (float*)alloc((size_t)N_NODES * sizeof(float));
  float* XXp  = (float*)alloc((size_t)NS * NS * sizeof(float));
  u64*   SUMC = (u64*)alloc((size_t)NS * NCH * sizeof(u64));         // 800 KB
  u64*   Lst  = (u64*)alloc((size_t)NS * KL * sizeof(u64));          // 96 KB

  k_xx   <<<NS, NS, 0, stream>>>(X, XXp);
  k_dist <<<(N_NODES + 127) / 128, 256, 0, stream>>>(X, V, XXp, P, PT, Q, SUMC);
  k_build<<<NS, 1024, 0, stream>>>(SUMC, P, Lst);
  k_seq  <<<1, 192, 0, stream>>>(PT, Q, XXp, Lst, itp, out);
}

// Round 8
// 305.281 us; speedup vs baseline: 1.0177x; 1.0100x over previous
//
#include <hip/hip_runtime.h>
#include <math.h>

// SOINN+ restructured, round 15:
//  k_xx    : unchanged.
//  k_dist  : 64-node tile (1563 blocks -> ~6 blocks/CU, was 3) to double
//            latency-hiding occupancy (R14 counters: VALUBusy 31%, HBM 16%,
//            Occupancy 19.7% = latency-bound at 3 waves/SIMD). V global
//            loads remapped 4-threads-per-row (128B coalesced segments).
//            Per-(s,n) FMA chains, qa chain, epilogue, SUMC min bitwise
//            preserved; one block = one SUMC chunk. pk-FMA retained.
//  k_build : unchanged from round 8.
//  k_seq   : byte-identical to the verified R10 form (81.5us).

#define N_NODES 100000
#define DIM     256
#define NS      64
#define NCH     1563
#define KC      32
#define NBMW    3125
#define CAP     4096
#define KL      192
#define KLS     136

typedef unsigned long long u64;
typedef __attribute__((ext_vector_type(2))) float f32x2;

__device__ __forceinline__ u64 pk(float d, int i) {
  return ((u64)__float_as_uint(d) << 32) | (unsigned)i;
}
// tracked-provenance key: bit31 flag, slot<<17 (slot<128), node in low 17 bits
__device__ __forceinline__ u64 tkey(float d, int slot, int node) {
  return ((u64)__float_as_uint(d) << 32) |
         (u64)(0x80000000u | ((unsigned)slot << 17) | (unsigned)node);
}
__device__ __forceinline__ u64 umin64(u64 a, u64 b) { return a < b ? a : b; }
__device__ __forceinline__ u64 umax64(u64 a, u64 b) { return a > b ? a : b; }
__device__ __forceinline__ void mrg2(u64& A0, u64& A1, u64 B0, u64 B1) {
  u64 m = umax64(A0, B0);
  A0 = umin64(A0, B0);
  A1 = umin64(umin64(A1, B1), m);
}

// packed dual FMA: acc.lo += x.sel * v.lo ; acc.hi += x.sel * v.hi
// _lo: broadcast word0 of xpair; _hi: broadcast word1.
__device__ __forceinline__ void pkfma_lo(f32x2& acc, f32x2 xp, f32x2 vp) {
  asm("v_pk_fma_f32 %0, %1, %2, %0 op_sel:[0,0,0] op_sel_hi:[0,1,1]"
      : "+v"(acc) : "v"(xp), "v"(vp));
}
__device__ __forceinline__ void pkfma_hi(f32x2& acc, f32x2 xp, f32x2 vp) {
  asm("v_pk_fma_f32 %0, %1, %2, %0 op_sel:[1,0,0] op_sel_hi:[1,1,1]"
      : "+v"(acc) : "v"(xp), "v"(vp));
}

template <int C>
__device__ __forceinline__ u64 dpp64(u64 x) {
  unsigned lo = (unsigned)__builtin_amdgcn_update_dpp(
      (int)0xFFFFFFFF, (int)(unsigned)(x & 0xFFFFFFFFull), C, 0xF, 0xF, false);
  unsigned hi = (unsigned)__builtin_amdgcn_update_dpp(
      (int)0xFFFFFFFF, (int)(unsigned)(x >> 32), C, 0xF, 0xF, false);
  return ((u64)hi << 32) | lo;
}
template <int C>
__device__ __forceinline__ void dpp_round(u64& A0, u64& A1) {
  u64 B0 = dpp64<C>(A0);
  u64 B1 = dpp64<C>(A1);
  mrg2(A0, A1, B0, B1);
}

__global__ void k_xx(const float* __restrict__ X, float* __restrict__ XX) {
  int i = blockIdx.x, j = threadIdx.x;
  const float* xi = X + i * DIM;
  const float* xj = X + j * DIM;
  float acc = 0.f;
  for (int k = 0; k < DIM; k += 4) {
    float4 a = *(const float4*)(xi + k);
    float4 b = *(const float4*)(xj + k);
    acc += a.x * b.x + a.y * b.y + a.z * b.z + a.w * b.w;
  }
  XX[i * NS + j] = acc;
}

__global__ __launch_bounds__(256) void k_dist(const float* __restrict__ X,
                                              const float* __restrict__ V,
                                              const float* __restrict__ XX,
                                              float* __restrict__ P,
                                              float* __restrict__ PT,
                                              float* __restrict__ Q,
                                              u64* __restrict__ SUMC) {
  __shared__ float Xl[KC][68];     // 64 samples, k-major (rows 16B-aligned)
  __shared__ float Vl[KC][66];     // 64 nodes, k-major (+2 pad; b64-aligned)
  __shared__ float sq[64];
  const int tid = threadIdx.x;     // 256 threads
  const int n0  = blockIdx.x * 64;
  const int ty  = tid >> 5;        // 0..7  -> samples 8ty..8ty+7
  const int tx  = tid & 31;        // 0..31 -> nodes 2tx..2tx+1
  f32x2 acc2[8];                   // acc2[i] = {acc[i](2tx), acc[i](2tx+1)}
#pragma unroll
  for (int i = 0; i < 8; i++) { acc2[i][0] = 0.f; acc2[i][1] = 0.f; }
  float qa = 0.f;
  const int xsl = tid & 63;            // sample row for X staging
  const int xkk = (tid >> 6) * 8;      // 4 wave-groups cover k-offsets 0,8,16,24
  const int vrw = tid >> 2;            // V row 0..63 (4 threads/row)
  const int vkk = (tid & 3) * 8;       // k-offsets 0,8,16,24 (128B coalesced)
  const bool vok = (n0 + vrw < N_NODES);
  const float* vrow = V + (size_t)(n0 + vrw) * DIM + vkk;
  const float* xrow = X + xsl * DIM + xkk;

  float4 xr0, xr1, vr0, vr1;
  // prefetch chunk 0
  xr0 = *(const float4*)(xrow + 0);
  xr1 = *(const float4*)(xrow + 4);
  vr0 = vok ? *(const float4*)(vrow + 0) : make_float4(0.f, 0.f, 0.f, 0.f);
  vr1 = vok ? *(const float4*)(vrow + 4) : make_float4(0.f, 0.f, 0.f, 0.f);

  for (int c = 0; c < 8; c++) {
    __syncthreads();
    // stage regs -> LDS (X and V both k-major)
    Xl[xkk + 0][xsl] = xr0.x; Xl[xkk + 1][xsl] = xr0.y;
    Xl[xkk + 2][xsl] = xr0.z; Xl[xkk + 3][xsl] = xr0.w;
    Xl[xkk + 4][xsl] = xr1.x; Xl[xkk + 5][xsl] = xr1.y;
    Xl[xkk + 6][xsl] = xr1.z; Xl[xkk + 7][xsl] = xr1.w;
    Vl[vkk + 0][vrw] = vr0.x; Vl[vkk + 1][vrw] = vr0.y;
    Vl[vkk + 2][vrw] = vr0.z; Vl[vkk + 3][vrw] = vr0.w;
    Vl[vkk + 4][vrw] = vr1.x; Vl[vkk + 5][vrw] = vr1.y;
    Vl[vkk + 6][vrw] = vr1.z; Vl[vkk + 7][vrw] = vr1.w;
    __syncthreads();
    // prefetch next chunk (latency hides under qa + FMA below)
    if (c + 1 < 8) {
      int kc = (c + 1) * KC;
      xr0 = *(const float4*)(xrow + kc);
      xr1 = *(const float4*)(xrow + kc + 4);
      vr0 = vok ? *(const float4*)(vrow + kc) : make_float4(0.f, 0.f, 0.f, 0.f);
      vr1 = vok ? *(const float4*)(vrow + kc + 4) : make_float4(0.f, 0.f, 0.f, 0.f);
    }
    // ||v||^2 chunk partial — node n0+tid, k ascending (bitwise chain)
    if (tid < 64) {
      float qq = 0.f;
#pragma unroll 8
      for (int k = 0; k < KC; k++) { float t = Vl[k][tid]; qq += t * t; }
      qa += qq;
    }
    // 8x2 register-tile FMA, k ascending, packed dual-FMA form.
    // acc2[i] chains are the exact per-element chains (fused FMA, k order).
#pragma unroll 4
    for (int k = 0; k < KC; k++) {
      float4 xa = *(const float4*)&Xl[k][ty * 8];      // broadcast (free)
      float4 xb = *(const float4*)&Xl[k][ty * 8 + 4];  // broadcast (free)
      f32x2 vp = *(const f32x2*)&Vl[k][tx * 2];        // b64, 2-way (free)
      f32x2 xp0, xp1, xp2, xp3;
      xp0[0] = xa.x; xp0[1] = xa.y;
      xp1[0] = xa.z; xp1[1] = xa.w;
      xp2[0] = xb.x; xp2[1] = xb.y;
      xp3[0] = xb.z; xp3[1] = xb.w;
      pkfma_lo(acc2[0], xp0, vp);
      pkfma_hi(acc2[1], xp0, vp);
      pkfma_lo(acc2[2], xp1, vp);
      pkfma_hi(acc2[3], xp1, vp);
      pkfma_lo(acc2[4], xp2, vp);
      pkfma_hi(acc2[5], xp2, vp);
      pkfma_lo(acc2[6], xp3, vp);
      pkfma_hi(acc2[7], xp3, vp);
    }
  }
  // unpack to scalar view for the epilogue (expressions unchanged)
  float acc[8][2];
#pragma unroll
  for (int i = 0; i < 8; i++) { acc[i][0] = acc2[i][0]; acc[i][1] = acc2[i][1]; }
  if (tid < 64) sq[tid] = qa;
  __syncthreads();
  if (tid < 64 && n0 + tid < N_NODES) Q[n0 + tid] = qa;
  float qs[2];
  *(f32x2*)&qs[0] = *(const f32x2*)&sq[tx * 2];
  const bool full = (n0 + 64) <= N_NODES;
#pragma unroll
  for (int i = 0; i < 8; i++) {
    int s = ty * 8 + i;
    float xn = XX[s * NS + s];
#pragma unroll
    for (int u = 0; u < 2; u++) acc[i][u] = xn - 2.f * acc[i][u] + qs[u];
    float* prow = P + (size_t)s * N_NODES + n0 + tx * 2;
    if (full) {
      *(float2*)(prow) = make_float2(acc[i][0], acc[i][1]);
    } else {
#pragma unroll
      for (int u = 0; u < 2; u++) {
        int n = n0 + tx * 2 + u;
        if (n < N_NODES) prow[u] = acc[i][u];
      }
    }
  }
#pragma unroll
  for (int u = 0; u < 2; u++) {
    int n = n0 + tx * 2 + u;
    if (n < N_NODES) {
      float* pt = PT + (size_t)n * NS + ty * 8;
      *(float4*)(pt)     = make_float4(acc[0][u], acc[1][u], acc[2][u], acc[3][u]);
      *(float4*)(pt + 4) = make_float4(acc[4][u], acc[5][u], acc[6][u], acc[7][u]);
    }
  }
  // fused per-chunk(64) min: this block IS chunk blockIdx.x (umin64 is
  // associative+exact over unique keys -> tree shape change is value-safe)
#pragma unroll
  for (int i = 0; i < 8; i++) {
    int s = ty * 8 + i;
    u64 key = ~0ull;
#pragma unroll
    for (int u = 0; u < 2; u++) {
      int n = n0 + tx * 2 + u;
      if (n < N_NODES) key = umin64(key, pk(acc[i][u], n));
    }
#pragma unroll
    for (int off = 1; off <= 16; off <<= 1)
      key = umin64(key, (u64)__shfl_xor((unsigned long long)key, off, 64));
    if (tx == 0) SUMC[(size_t)s * NCH + blockIdx.x] = key;
  }
}

// fused threshold + collect + sort: one block per sample
__global__ __launch_bounds__(1024) void k_build(const u64* __restrict__ SUMC,
                                                const float* __restrict__ P,
                                                u64* __restrict__ L) {
  __shared__ u64 A[CAP];            // 32 KB
  __shared__ u64 Twave[16];
  __shared__ float Tsh;
  __shared__ int cnt;
  const int j = blockIdx.x, tid = threadIdx.x;
  const int w = tid >> 6, l = tid & 63;
  // phase 1: per-wave 9th-smallest chunk-min; T = max over waves.
  {
    int base = w * 98;
    u64 v0 = (base + l < NCH) ? SUMC[(size_t)j * NCH + base + l] : ~0ull;
    u64 v1 = (l < 34 && base + 64 + l < NCH)
                 ? SUMC[(size_t)j * NCH + base + 64 + l] : ~0ull;
    u64 s9 = ~0ull;
#pragma unroll
    for (int r = 0; r < 9; r++) {
      u64 m = umin64(v0, v1);
#pragma unroll
      for (int off = 1; off <= 32; off <<= 1)
        m = umin64(m, (u64)__shfl_xor((unsigned long long)m, off, 64));
      if (r == 8) { s9 = m; } else {
        if (v0 == m) v0 = ~0ull;
        if (v1 == m) v1 = ~0ull;
      }
    }
    if (l == 0) Twave[w] = s9;
  }
  __syncthreads();
  if (tid == 0) {
    u64 t = 0;
    for (int i = 0; i < 16; i++) t = umax64(t, Twave[i]);
    Tsh = __uint_as_float((unsigned)(t >> 32));   // >=144 entries <= T guaranteed
    cnt = 0;
  }
  __syncthreads();
  const float T = Tsh;
  // phase 2: compact candidates (d <= T) into A
  const float* prow = P + (size_t)j * N_NODES;
  for (int n0 = tid * 4; n0 < N_NODES + 3; n0 += 4096) {
    float d[4];
    if (n0 + 3 < N_NODES) {
      float4 p = *(const float4*)(prow + n0);
      d[0] = p.x; d[1] = p.y; d[2] = p.z; d[3] = p.w;
    } else {
#pragma unroll
      for (int e = 0; e < 4; e++)
        d[e] = (n0 + e < N_NODES) ? prow[n0 + e] : INFINITY;
    }
#pragma unroll
    for (int e = 0; e < 4; e++) {
      if (d[e] <= T) {
        int pos = atomicAdd(&cnt, 1);
        if (pos < CAP) A[pos] = pk(d[e], n0 + e);
      }
    }
  }
  __syncthreads();
  int n = cnt; if (n > CAP) n = CAP;
  int M = 256; while (M < n) M <<= 1;
  for (int i = tid; i < M; i += 1024)
    if (i >= n) A[i] = ~0ull;
  __syncthreads();
  // phase 3: bitonic sort M
  for (int k = 2; k <= M; k <<= 1)
    for (int s2 = k >> 1; s2 > 0; s2 >>= 1) {
      for (int i = tid; i < M; i += 1024) {
        int p = i ^ s2;
        if (p > i) {
          u64 a = A[i], b = A[p];
          bool up = ((i & k) == 0);
          if ((a > b) == up) { A[i] = b; A[p] = a; }
        }
      }
      __syncthreads();
    }
  for (int i = tid; i < KLS; i += 1024) L[(size_t)j * KL + i] = A[i];
}

__global__ __launch_bounds__(192) void k_seq(
    const float* __restrict__ PT, const float* __restrict__ Q,
    const float* __restrict__ XXg, const u64* __restrict__ L,
    const int* __restrict__ itp, float* __restrict__ out) {
  __shared__ float XXl[NS * 65];         // 16640
  __shared__ float g[128][65];           // 33280
  __shared__ float qv[128];
  __shared__ unsigned int bitmap[NBMW];  // 12500 (wave0 writes, producers read)
  __shared__ int tracked[128];
  __shared__ u64 cand16[NS][16];         // 8192: first-16-untracked per step
  __shared__ float specg[4][6][NS];      // 6144: PT rows of first-6-untracked
  __shared__ float specq[4][6];
  __shared__ int   specid[4][6];
  __shared__ int readyC[NS];             // cand16[t] complete
  __shared__ int readyS[NS];             // specg/specq/specid[t&3] complete
  __shared__ int done[NS];

  const int tid = threadIdx.x;           // 192 = 3 waves
  const int wv = tid >> 6;
  const int lane = tid & 63;

  for (int i = tid; i < NS * NS; i += 192) {
    int r = i >> 6, c = i & 63;
    XXl[r * 65 + c] = XXg[i];
  }
  for (int i = tid; i < NBMW; i += 192) bitmap[i] = 0u;
  for (int i = tid; i < NS; i += 192) { readyC[i] = 0; readyS[i] = 0; done[i] = 0; }
  __syncthreads();

  const int it = itp[0];
  const float eps_b = 1.0f / (float)(it + 2);
  const float eps_n = 1.0f / (float)((it + 1) * 100);
  const float xdl = XXl[lane * 65 + lane];

  if (wv == 0) {
    // ================= consumer: pure LDS + VALU =================
    int ns = 0;
    int pw0 = -1, pw1 = -1, pw2 = -1, pw3 = -1;   // winners of steps j-1, j-2
    for (int j = 0; j < NS; j++) {
      while (__hip_atomic_load(&readyC[j], __ATOMIC_ACQUIRE,
                               __HIP_MEMORY_SCOPE_WORKGROUP) == 0)
        __builtin_amdgcn_s_sleep(1);
      const int sb = j & 3;
      u64 ck = (lane < 16) ? cand16[j][lane] : ~0ull;
      float gA = g[lane][j], gB = g[lane + 64][j];
      float qvA = qv[lane],  qvB = qv[lane + 64];
      int   tA = tracked[lane], tB = tracked[lane + 64];
      float xrow = XXl[j * 65 + lane];
      float xnj  = XXl[j * 65 + j];
      // candidates: compacted untracked list entry (patched vs last-4 winners)
      u64 A0 = ~0ull, A1 = ~0ull;
      {
        int id = (int)(unsigned)(ck & 0xFFFFFFFFull);
        bool ok = (ck != ~0ull) && id != pw0 && id != pw1 && id != pw2 && id != pw3;
        if (ok) { A0 = ck; }
      }
      // tracked algebraic distances (expression preserved; keys carry slot tag)
      if (lane < ns)      { float d = xnj - 2.f * gA + qvA; mrg2(A0, A1, tkey(d, lane, tA), ~0ull); }
      if (lane + 64 < ns) { float d = xnj - 2.f * gB + qvB; mrg2(A0, A1, tkey(d, lane + 64, tB), ~0ull); }
      // DPP min-2 -> exact top-2 in lane 63
      dpp_round<0x111>(A0, A1);
      dpp_round<0x112>(A0, A1);
      dpp_round<0x114>(A0, A1);
      dpp_round<0x118>(A0, A1);
      dpp_round<0x142>(A0, A1);
      dpp_round<0x143>(A0, A1);
      const unsigned lo0 = (unsigned)__builtin_amdgcn_readlane(
          (int)(unsigned)(A0 & 0xFFFFFFFFull), 63);
      const unsigned lo1 = (unsigned)__builtin_amdgcn_readlane(
          (int)(unsigned)(A1 & 0xFFFFFFFFull), 63);
      const int r0 = (int)(lo0 & 0x1FFFFu);
      const int r1 = (int)(lo1 & 0x1FFFFu);
      const bool new0 = (lo0 & 0x80000000u) == 0u;
      const bool new1 = (lo1 & 0x80000000u) == 0u;
      const int sl0 = new0 ? ns : (int)((lo0 >> 17) & 127u);
      const int sl1 = new1 ? (ns + (new0 ? 1 : 0)) : (int)((lo1 >> 17) & 127u);
      if (lane == 63) {
        float2 o;
        o.x = sqrtf(fmaxf(__uint_as_float((unsigned)(A0 >> 32)), 0.f) + 1e-12f);
        o.y = sqrtf(fmaxf(__uint_as_float((unsigned)(A1 >> 32)), 0.f) + 1e-12f);
        *(float2*)(out + j * 2) = o;
      }
      // issue slot-dependent LDS reads before the spec wait (overlap latency)
      float gt0 = g[sl0][lane];
      float gt1 = g[sl1][lane];
      // wait for specs only now — producer PT gather overlapped with reduce above
      while (__hip_atomic_load(&readyS[j], __ATOMIC_ACQUIRE,
                               __HIP_MEMORY_SCOPE_WORKGROUP) == 0)
        __builtin_amdgcn_s_sleep(1);
      float sgv[6], sqv[6]; int sid[6];
#pragma unroll
      for (int s = 0; s < 6; s++) {
        sgv[s] = specg[sb][s][lane];
        sid[s] = specid[sb][s];
        sqv[s] = specq[sb][s];
      }
      // spec select over 6 (values bitwise identical to direct loads)
      bool hit0 = false, hit1 = false;
      float pv0 = 0.f, qq0 = 0.f, pv1 = 0.f, qq1 = 0.f;
#pragma unroll
      for (int s = 0; s < 6; s++) {
        bool h0 = (sid[s] == r0), h1 = (sid[s] == r1);
        pv0 = h0 ? sgv[s] : pv0;  qq0 = h0 ? sqv[s] : qq0;  hit0 |= h0;
        pv1 = h1 ? sgv[s] : pv1;  qq1 = h1 ? sqv[s] : qq1;  hit1 |= h1;
      }
      if (new0 && !hit0) { pv0 = PT[(size_t)r0 * NS + lane]; qq0 = Q[r0]; } // never taken
      if (new1 && !hit1) { pv1 = PT[(size_t)r1 * NS + lane]; qq1 = Q[r1]; }
      // phase 0: r0 / eps_b
      float gold0 = new0 ? (0.5f * (xdl + qq0 - pv0)) : gt0;
      float qold0 = new0 ? qq0
                         : __uint_as_float((unsigned)__builtin_amdgcn_readlane(
                               (int)__float_as_uint(sl0 < 64 ? qvA : qvB), sl0 & 63));
      float gj0 = __uint_as_float(
          (unsigned)__builtin_amdgcn_readlane((int)__float_as_uint(gold0), j));
      g[sl0][lane] = (1.f - eps_b) * gold0 + eps_b * xrow;
      if (lane == 0) {
        float om = 1.f - eps_b;
        qv[sl0] = om * om * qold0 + 2.f * eps_b * om * gj0 + eps_b * eps_b * xnj;
        tracked[sl0] = r0;
        if (new0) bitmap[r0 >> 5] |= 1u << (r0 & 31);
      }
      // phase 1: r1 / eps_n
      float gold1 = new1 ? (0.5f * (xdl + qq1 - pv1)) : gt1;
      float qold1 = new1 ? qq1
                         : __uint_as_float((unsigned)__builtin_amdgcn_readlane(
                               (int)__float_as_uint(sl1 < 64 ? qvA : qvB), sl1 & 63));
      float gj1 = __uint_as_float(
          (unsigned)__builtin_amdgcn_readlane((int)__float_as_uint(gold1), j));
      g[sl1][lane] = (1.f - eps_n) * gold1 + eps_n * xrow;
      if (lane == 0) {
        float on = 1.f - eps_n;
        qv[sl1] = on * on * qold1 + 2.f * eps_n * on * gj1 + eps_n * eps_n * xnj;
        tracked[sl1] = r1;
        if (new1) bitmap[r1 >> 5] |= 1u << (r1 & 31);
      }
      ns += (new0 ? 1 : 0) + (new1 ? 1 : 0);
      pw2 = pw0; pw3 = pw1; pw0 = r0; pw1 = r1;
      __hip_atomic_store(&done[j], 1, __ATOMIC_RELEASE,
                         __HIP_MEMORY_SCOPE_WORKGROUP);
    }
  } else {
    // ========== producers (wv=1: even t, wv=2: odd t), wait done[t-3] ==========
    for (int t = (wv == 1 ? 0 : 1); t < NS; t += 2) {
      // L is read-only in this kernel: issue loads BEFORE the wait so their
      // latency hides under the spin.
      const u64* Lr = L + (size_t)t * KL;
      u64 e0 = Lr[lane], e1 = Lr[lane + 64];
      u64 e2 = (lane < 8) ? Lr[128 + lane] : ~0ull;
      if (t >= 3) {
        while (__hip_atomic_load(&done[t - 3], __ATOMIC_ACQUIRE,
                                 __HIP_MEMORY_SCOPE_WORKGROUP) == 0)
          __builtin_amdgcn_s_sleep(1);
      }
      int i0 = (int)(unsigned)(e0 & 0xFFFFFFFFull);
      int i1 = (int)(unsigned)(e1 & 0xFFFFFFFFull);
      int i2 = (int)(unsigned)(e2 & 0xFFFFFFFFull);
      bool t0 = (e0 == ~0ull) || ((bitmap[i0 >> 5] >> (i0 & 31)) & 1u);
      bool t1 = (e1 == ~0ull) || ((bitmap[i1 >> 5] >> (i1 & 31)) & 1u);
      bool t2 = (e2 == ~0ull) || ((bitmap[i2 >> 5] >> (i2 & 31)) & 1u);
      u64 um0 = ~__ballot(t0), um1 = ~__ballot(t1), um2 = ~__ballot(t2);
      u64 below = (1ull << lane) - 1;
      int c0n = __popcll((unsigned long long)um0);
      int c1n = __popcll((unsigned long long)um1);
      int rank0 = __popcll((unsigned long long)(um0 & below));
      int rank1 = c0n + __popcll((unsigned long long)(um1 & below));
      int rank2 = c0n + c1n + __popcll((unsigned long long)(um2 & below));
      if (!t0 && rank0 < 16) cand16[t][rank0] = e0;
      if (!t1 && rank1 < 16) cand16[t][rank1] = e1;
      if (!t2 && rank2 < 16) cand16[t][rank2] = e2;
      int U = c0n + c1n + __popcll((unsigned long long)um2);
      if (lane < 16 && lane >= U) cand16[t][lane] = ~0ull;
      // cand16 complete: release to consumer before the slow PT gather
      __hip_atomic_store(&readyC[t], 1, __ATOMIC_RELEASE,
                         __HIP_MEMORY_SCOPE_WORKGROUP);
      // spec: first-6-untracked PT/Q (U >= 136-126 = 10 >= 6 always)
      const int sb = t & 3;
      int ids[6];
#pragma unroll
      for (int s = 0; s < 6; s++)
        ids[s] = (int)(unsigned)(cand16[t][s] & 0xFFFFFFFFull);
#pragma unroll
      for (int s = 0; s < 6; s++)
        specg[sb][s][lane] = PT[(size_t)ids[s] * NS + lane];
      if (lane < 6) {
        specid[sb][lane] = ids[lane];
        specq[sb][lane] = Q[ids[lane]];
      }
      __hip_atomic_store(&readyS[t], 1, __ATOMIC_RELEASE,
                         __HIP_MEMORY_SCOPE_WORKGROUP);
    }
  }
}

extern "C" void kernel_launch(void* const* d_in, const int* in_sizes, int n_in,
                              void* d_out, int out_size, void* d_ws, size_t ws_size,
                              hipStream_t stream) {
  const float* X  = (const float*)d_in[0];  // [64,256]
  const float* V  = (const float*)d_in[1];  // [100000,256]
  const int*  itp = (const int*)d_in[3];    // scalar it
  float* out = (float*)d_out;               // [64,2]

  char* ws = (char*)d_ws;
  size_t off = 0;
  auto alloc = [&](size_t bytes) -> void* {
    size_t o = (off + 255) & ~(size_t)255;
    off = o + bytes;
    return (void*)(ws + o);
  };
  float* P    = (float*)alloc((size_t)NS * N_NODES * sizeof(float)); // 25.6 MB
  float* PT   = (float*)alloc((size_t)NS * N_NODES * sizeof(float)); // 25.6 MB
  float* Q    = (float*)alloc((size_t)N_NODES * sizeof(float));
  float* XXp  = (float*)alloc((size_t)NS * NS * sizeof(float));
  u64*   SUMC = (u64*)alloc((size_t)NS * NCH * sizeof(u64));         // 800 KB
  u64*   Lst  = (u64*)alloc((size_t)NS * KL * sizeof(u64));          // 96 KB

  k_xx   <<<NS, NS, 0, stream>>>(X, XXp);
  k_dist <<<(N_NODES + 63) / 64, 256, 0, stream>>>(X, V, XXp, P, PT, Q, SUMC);
  k_build<<<NS, 1024, 0, stream>>>(SUMC, P, Lst);
  k_seq  <<<1, 192, 0, stream>>>(PT, Q, XXp, Lst, itp, out);
}